// Round 1
// baseline (308.775 us; speedup 1.0000x reference)
//
#include <hip/hip_runtime.h>
#include <math.h>

// SpectralBias: B=1,H=16,L=2048,DH=64, M=2 modes, K=6 freqs, HIDDEN=128, OUT=9
// out[b,h,i,j] = mask(i>=j) * ( sum_k C[h,i,k] cos(w_k (i-j)) + S[h,i,k] sin(w_k (i-j))
//                               - b0[h,i] - slope[h,i]/64 * (i-j) )

struct BiasParams {
    float omg[6];   // omega_k (np.logspace(..).astype(f32))
    float omg2[6];  // omega_k^2
    float cw[6];    // cos(omega_k)
    float sw[6];    // sin(omega_k)
};

__device__ __forceinline__ float sigmoidf_(float x) { return 1.0f / (1.0f + expf(-x)); }
__device__ __forceinline__ float softplusf_(float x) {
    // jax.nn.softplus: max(x,0) + log1p(exp(-|x|))  (stable, matches fp32)
    return fmaxf(x, 0.0f) + log1pf(expf(-fabsf(x)));
}

// ---------------- Kernel 0: cos/sin means over Delta in [0, 2048) ----------------
// ws[0..5] = cos_mean[k], ws[6..11] = sin_mean[k]
__global__ void sb_mean_kernel(float* __restrict__ ws, BiasParams P)
{
    const int k    = threadIdx.x >> 6;   // 6 waves, one per frequency
    const int lane = threadIdx.x & 63;
    const float om = P.omg[k];
    float cacc = 0.f, sacc = 0.f;
    for (int d = lane; d < 2048; d += 64) {
        float s, c;
        sincosf(om * (float)d, &s, &c);
        cacc += c; sacc += s;
    }
    #pragma unroll
    for (int off = 32; off >= 1; off >>= 1) {
        cacc += __shfl_down(cacc, off);
        sacc += __shfl_down(sacc, off);
    }
    if (lane == 0) {
        ws[k]     = cacc * (1.0f / 2048.0f);
        ws[6 + k] = sacc * (1.0f / 2048.0f);
    }
}

// ---------------- Kernel 1: per-query MLP -> {C[6], S[6], b0, slope/64} ----------------
// Block: 256 threads = 4 waves, 64 queries per block (lane = query).
// Wave w computes hidden units [32w, 32w+32) for all 64 queries.
__global__ __launch_bounds__(256) void sb_coef_kernel(
    const float* __restrict__ q,  const float* __restrict__ w1,
    const float* __restrict__ b1, const float* __restrict__ w2,
    const float* __restrict__ b2, float* __restrict__ ws, BiasParams P)
{
    __shared__ __align__(16) float w1L[64 * 132];  // [d][h] transposed, pad 132 (8-way wr conflict, cheap)
    __shared__ __align__(16) float w2L[9 * 128];   // as-is, read as wave-uniform broadcast
    __shared__ __align__(16) float qs[64 * 65];    // [query][d] pad 65; reused as partial[4][64][13]

    const int t      = threadIdx.x;
    const int lane   = t & 63;
    const int w      = t >> 6;
    const int qblock = blockIdx.x << 6;

    // stage w1 transposed: w1 is [128][64] row-major -> w1L[d*132+h]
    for (int idx = t; idx < 128 * 64; idx += 256) {
        int h = idx >> 6, d = idx & 63;
        w1L[d * 132 + h] = w1[idx];
    }
    for (int idx = t; idx < 9 * 128; idx += 256) w2L[idx] = w2[idx];
    {
        const float* qg = q + ((size_t)qblock << 6);
        for (int idx = t; idx < 64 * 64; idx += 256)
            qs[(idx >> 6) * 65 + (idx & 63)] = qg[idx];
    }
    __syncthreads();

    const int h0 = w << 5;
    float acc[32];
    #pragma unroll
    for (int u = 0; u < 32; ++u) acc[u] = b1[h0 + u];   // wave-uniform broadcast load

    // layer 1: 1 LDS read + 32 FMA per d  (w1L reads are wave-uniform -> LDS broadcast)
    for (int d = 0; d < 64; ++d) {
        float qv = qs[lane * 65 + d];
        const float4* wr = (const float4*)(&w1L[d * 132 + h0]);
        #pragma unroll
        for (int u4 = 0; u4 < 8; ++u4) {
            float4 wv = wr[u4];
            acc[u4 * 4 + 0] = fmaf(qv, wv.x, acc[u4 * 4 + 0]);
            acc[u4 * 4 + 1] = fmaf(qv, wv.y, acc[u4 * 4 + 1]);
            acc[u4 * 4 + 2] = fmaf(qv, wv.z, acc[u4 * 4 + 2]);
            acc[u4 * 4 + 3] = fmaf(qv, wv.w, acc[u4 * 4 + 3]);
        }
    }
    // SiLU
    #pragma unroll
    for (int u = 0; u < 32; ++u) acc[u] = acc[u] * sigmoidf_(acc[u]);

    // layer 2 partials over this wave's hidden slice
    float part[9];
    #pragma unroll
    for (int o = 0; o < 9; ++o) part[o] = 0.f;
    #pragma unroll
    for (int o = 0; o < 9; ++o) {
        const float4* wr = (const float4*)(&w2L[o * 128 + h0]);
        #pragma unroll
        for (int u4 = 0; u4 < 8; ++u4) {
            float4 wv = wr[u4];
            part[o] = fmaf(acc[u4 * 4 + 0], wv.x, part[o]);
            part[o] = fmaf(acc[u4 * 4 + 1], wv.y, part[o]);
            part[o] = fmaf(acc[u4 * 4 + 2], wv.z, part[o]);
            part[o] = fmaf(acc[u4 * 4 + 3], wv.w, part[o]);
        }
    }
    __syncthreads();                  // qs no longer needed -> reuse as partials
    float* pl = qs;                   // [4 waves][64 queries][13] (stride 13: conflict-free)
    #pragma unroll
    for (int o = 0; o < 9; ++o) pl[t * 13 + o] = part[o];
    __syncthreads();

    if (w == 0) {
        float y[9];
        #pragma unroll
        for (int o = 0; o < 9; ++o)
            y[o] = b2[o] + pl[lane * 13 + o] + pl[(64 + lane) * 13 + o]
                 + pl[(128 + lane) * 13 + o] + pl[(192 + lane) * 13 + o];

        float C[6], S[6];
        #pragma unroll
        for (int k = 0; k < 6; ++k) { C[k] = 0.f; S[k] = 0.f; }
        float slope = softplusf_(y[8]);

        #pragma unroll
        for (int m = 0; m < 2; ++m) {
            float p   = sigmoidf_(y[m]);
            float dst = sigmoidf_(y[2 + m]) * 2047.0f;            // delta*
            float sg  = 32.0f + sigmoidf_(y[4 + m]) * 224.0f;     // sigma
            float cm  = 0.01f * softplusf_(y[6 + m]);             // c
            float s2  = sg * sg;
            float a[6]; float asum = 0.f;
            #pragma unroll
            for (int k = 0; k < 6; ++k) { a[k] = expf(-0.5f * P.omg2[k] * s2); asum += a[k]; }
            float inv = 1.0f / (asum + 1e-9f);
            float pc  = p * cm;
            #pragma unroll
            for (int k = 0; k < 6; ++k) {
                float sn, cn;
                sincosf(P.omg[k] * dst, &sn, &cn);
                float amp = pc * (a[k] * inv);
                C[k] = fmaf(amp, cn, C[k]);
                S[k] = fmaf(amp, sn, S[k]);
            }
        }
        float b0 = 0.f;
        #pragma unroll
        for (int k = 0; k < 6; ++k) b0 += C[k] * ws[k] + S[k] * ws[6 + k];

        float* cf = ws + 16 + ((size_t)(qblock + lane) << 4);
        ((float4*)cf)[0] = make_float4(C[0], C[1], C[2], C[3]);
        ((float4*)cf)[1] = make_float4(C[4], C[5], S[0], S[1]);
        ((float4*)cf)[2] = make_float4(S[2], S[3], S[4], S[5]);
        ((float4*)cf)[3] = make_float4(b0, slope * (1.0f / 64.0f), 0.f, 0.f);
    }
}

// ---------------- Kernel 2: bias fill, one block per (h,i) row ----------------
// Thread t handles 8 consecutive j via phasor recurrence (no per-element trig).
__global__ __launch_bounds__(256) void sb_bias_kernel(
    const float* __restrict__ ws, float* __restrict__ out, BiasParams P)
{
    const int rid = blockIdx.x;        // h*2048 + i
    const int i   = rid & 2047;
    const float* cf = ws + 16 + ((size_t)rid << 4);
    const float4 c0 = ((const float4*)cf)[0];
    const float4 c1 = ((const float4*)cf)[1];
    const float4 c2 = ((const float4*)cf)[2];
    const float4 c3 = ((const float4*)cf)[3];
    const float C[6] = {c0.x, c0.y, c0.z, c0.w, c1.x, c1.y};
    const float S[6] = {c1.z, c1.w, c2.x, c2.y, c2.z, c2.w};
    const float b0 = c3.x, slt = c3.y;

    const int j0 = threadIdx.x << 3;
    const int D0 = i - j0;             // Delta at first element (descends with s)
    float res[8];

    if (D0 < 0) {
        #pragma unroll
        for (int s = 0; s < 8; ++s) res[s] = 0.f;
    } else {
        // g_k = C cos(wD)+S sin(wD); h_k = S cos(wD)-C sin(wD); rotate to advance D -> D-1
        float g[6], hh[6];
        #pragma unroll
        for (int k = 0; k < 6; ++k) {
            float sn, cn;
            __sincosf(P.omg[k] * (float)D0, &sn, &cn);
            g[k]  = fmaf(C[k], cn,  S[k] * sn);
            hh[k] = fmaf(S[k], cn, -C[k] * sn);
        }
        float dpf = (float)D0;
        #pragma unroll
        for (int s = 0; s < 8; ++s) {
            float four = ((g[0] + g[1]) + (g[2] + g[3])) + (g[4] + g[5]);
            res[s] = (s <= D0) ? (four - b0 - slt * dpf) : 0.f;
            #pragma unroll
            for (int k = 0; k < 6; ++k) {
                float gn = fmaf(g[k],  P.cw[k], -hh[k] * P.sw[k]);
                float hn = fmaf(hh[k], P.cw[k],  g[k]  * P.sw[k]);
                g[k] = gn; hh[k] = hn;
            }
            dpf -= 1.0f;
        }
    }
    float4* op = (float4*)(out + (((size_t)rid) << 11) + j0);
    op[0] = make_float4(res[0], res[1], res[2], res[3]);
    op[1] = make_float4(res[4], res[5], res[6], res[7]);
}

extern "C" void kernel_launch(void* const* d_in, const int* in_sizes, int n_in,
                              void* d_out, int out_size, void* d_ws, size_t ws_size,
                              hipStream_t stream) {
    const float* q  = (const float*)d_in[0];
    const float* w1 = (const float*)d_in[1];
    const float* b1 = (const float*)d_in[2];
    const float* w2 = (const float*)d_in[3];
    const float* b2 = (const float*)d_in[4];
    float* out = (float*)d_out;
    float* ws  = (float*)d_ws;

    BiasParams P;
    const double l0 = log10(2.0 * M_PI / 1.0e6);     // log10(w_min)
    const double l1 = log10(2.0 * M_PI / 2048.0);    // log10(w_max)
    for (int k = 0; k < 6; ++k) {
        double e  = l0 + (l1 - l0) * ((double)k / 5.0);
        float  wf = (float)pow(10.0, e);             // matches np.logspace(...).astype(f32)
        P.omg[k]  = wf;
        P.omg2[k] = wf * wf;
        P.cw[k]   = (float)cos((double)wf);
        P.sw[k]   = (float)sin((double)wf);
    }

    sb_mean_kernel<<<1, 384, 0, stream>>>(ws, P);
    sb_coef_kernel<<<512, 256, 0, stream>>>(q, w1, b1, w2, b2, ws, P);
    sb_bias_kernel<<<16 * 2048, 256, 0, stream>>>(ws, out, P);
}